// Round 6
// baseline (262.231 us; speedup 1.0000x reference)
//
#include <hip/hip_runtime.h>
#include <math.h>

#define NROWS 16384
#define INDIM 2048
#define NE 16
#define RPB 16                    // rows per block (4 waves x 4 rows)
#define RPW 4                     // rows per wave
#define KSTEP 256                 // k covered per iteration (64 lanes x float4)
#define NITER (INDIM / KSTEP)     // 8
#define EG 4                      // experts per W1 load-group
#define NG (NE / EG)              // 4 groups per iteration

// (256,3): 170-VGPR cap. Evidence trail: (256,4)=128 cap -> acc spilled to
// AGPRs (VGPR=56, 2.7x VALU tax, 78us). (256,2)=256 cap fixed the spill but
// left only 2 waves/SIMD of TLP (~1200cyc prefetch distance vs ~900cyc HBM
// latency, 68us). Steady-state working set ~148 regs fits 170 -> 3 waves/SIMD.
__global__ __launch_bounds__(256, 3) void gate_kernel(
    const float* __restrict__ x,
    const float* __restrict__ W1,
    const float* __restrict__ W2,
    float* __restrict__ out)
{
    __shared__ float hbuf[RPB][17];
    __shared__ float w2s[NE * NE];

    const int tid  = threadIdx.x;
    const int lane = tid & 63;
    const int wv   = tid >> 6;                       // 0..3
    const int rowW = blockIdx.x * RPB + wv * RPW;    // wave's first row

    if (tid < 64) ((float4*)w2s)[tid] = ((const float4*)W2)[tid];

    float acc[RPW * NE];
    #pragma unroll
    for (int i = 0; i < RPW * NE; ++i) acc[i] = 0.0f;

    const float* xw  = x  + (size_t)rowW * INDIM + lane * 4;  // per-lane, coalesced
    const float* w1l = W1 + lane * 4;                          // per-lane, coalesced

    float4 xv_cur[RPW], xv_nxt[RPW];
    float4 wq_cur[EG], wq_nxt[EG];

    #pragma unroll
    for (int r = 0; r < RPW; ++r)
        xv_cur[r] = *(const float4*)(xw + (size_t)r * INDIM);
    #pragma unroll
    for (int e = 0; e < EG; ++e)
        wq_cur[e] = *(const float4*)(w1l + (size_t)e * INDIM);

    #pragma unroll 1
    for (int it = 0; it < NITER; ++it) {
        // prefetch next iteration's x (awaited ~1 iter = ~1800 wall-cycles later)
        if (it + 1 < NITER) {
            #pragma unroll
            for (int r = 0; r < RPW; ++r)
                xv_nxt[r] = *(const float4*)(xw + (size_t)r * INDIM + (it + 1) * KSTEP);
        }

        #pragma unroll
        for (int g = 0; g < NG; ++g) {
            // prefetch next expert-group (wraps into next iteration's group 0)
            const int nit = (g + 1 < NG) ? it : it + 1;
            const int ng  = (g + 1) & (NG - 1);
            if (nit < NITER) {
                #pragma unroll
                for (int e = 0; e < EG; ++e)
                    wq_nxt[e] = *(const float4*)(w1l + (size_t)(ng * EG + e) * INDIM
                                                     + (size_t)nit * KSTEP);
            }
            // FMA current group while next group's loads are in flight
            #pragma unroll
            for (int r = 0; r < RPW; ++r) {
                #pragma unroll
                for (int e = 0; e < EG; ++e) {
                    float a = acc[r * NE + g * EG + e];
                    a = fmaf(xv_cur[r].x, wq_cur[e].x, a);
                    a = fmaf(xv_cur[r].y, wq_cur[e].y, a);
                    a = fmaf(xv_cur[r].z, wq_cur[e].z, a);
                    a = fmaf(xv_cur[r].w, wq_cur[e].w, a);
                    acc[r * NE + g * EG + e] = a;
                }
            }
            #pragma unroll
            for (int e = 0; e < EG; ++e) wq_cur[e] = wq_nxt[e];
        }
        #pragma unroll
        for (int r = 0; r < RPW; ++r) xv_cur[r] = xv_nxt[r];
    }

    // ---- folding butterfly: reduce 64 values across 64 lanes in 63 shuffles ----
    #pragma unroll
    for (int s = 0; s < 6; ++s) {
        const int m = 1 << s;
        const int h = 32 >> s;
        const int b = (lane >> s) & 1;
        #pragma unroll
        for (int i = 0; i < h; ++i) {
            const float keep = b ? acc[i + h] : acc[i];
            const float send = b ? acc[i] : acc[i + h];
            acc[i] = keep + __shfl_xor(send, m, 64);
        }
    }
    {
        int v = 0;
        #pragma unroll
        for (int s = 0; s < 6; ++s) v |= ((lane >> s) & 1) << (5 - s);
        hbuf[wv * RPW + (v >> 4)][v & 15] = tanhf(acc[0]);
    }
    __syncthreads();

    // ---- per-row tail: logits, sort, softmax, k policy, outputs ----
    if (tid < RPB) {
        const int r   = tid;
        const int row = blockIdx.x * RPB + r;

        float hr[NE];
        #pragma unroll
        for (int e = 0; e < NE; ++e) hr[e] = hbuf[r][e];

        float v[NE];
        int   idx[NE];
        #pragma unroll
        for (int f = 0; f < NE; ++f) {
            float s = 0.0f;
            #pragma unroll
            for (int j = 0; j < 4; ++j) {
                const float4 w = ((const float4*)w2s)[f * 4 + j];
                s = fmaf(hr[4 * j + 0], w.x, s);
                s = fmaf(hr[4 * j + 1], w.y, s);
                s = fmaf(hr[4 * j + 2], w.z, s);
                s = fmaf(hr[4 * j + 3], w.w, s);
            }
            v[f]   = s / 0.7f;
            idx[f] = f;
        }

        // bitonic sort on key (-value, index): stable descending argsort
        #pragma unroll
        for (int ksz = 2; ksz <= 16; ksz <<= 1) {
            #pragma unroll
            for (int jsz = ksz >> 1; jsz >= 1; jsz >>= 1) {
                #pragma unroll
                for (int i = 0; i < 16; ++i) {
                    const int l = i ^ jsz;
                    if (l > i) {
                        const bool asc   = ((i & ksz) == 0);
                        const bool keyGt = (v[i] < v[l]) ||
                                           (v[i] == v[l] && idx[i] > idx[l]);
                        if (keyGt == asc) {
                            float tv = v[i]; v[i] = v[l]; v[l] = tv;
                            int   ti = idx[i]; idx[i] = idx[l]; idx[l] = ti;
                        }
                    }
                }
            }
        }

        float p[NE];
        float tot = 0.0f;
        #pragma unroll
        for (int i = 0; i < NE; ++i) { p[i] = expf(v[i] - v[0]); tot += p[i]; }
        #pragma unroll
        for (int i = 0; i < NE; ++i) p[i] = p[i] / tot;

        float cum[NE];
        cum[0] = p[0];
        #pragma unroll
        for (int i = 1; i < NE; ++i) cum[i] = cum[i - 1] + p[i];

        int k = NE;
        #pragma unroll
        for (int i = NE - 1; i >= 0; --i) if (cum[i] >= 0.92f) k = i + 1;

        if ((p[0] >= 0.46f) && ((p[0] - p[1]) >= 0.1f)) k = 1;
        if ((k > 2) && ((cum[1] >= 0.82f) || (p[2] <= 0.12f) || ((p[1] - p[2]) <= 0.03f)))
            k = 2;
        k = k < 1 ? 1 : (k > 3 ? 3 : k);

        const float4 o0 = make_float4((float)idx[0], (float)idx[1], (float)idx[2], (float)idx[3]);
        const float4 o1 = make_float4((float)idx[4], (float)idx[5], (float)idx[6], (float)idx[7]);
        const float4 s0 = make_float4(k > 0 ? p[0] : 0.0f, k > 1 ? p[1] : 0.0f,
                                      k > 2 ? p[2] : 0.0f, k > 3 ? p[3] : 0.0f);
        const float4 s1 = make_float4(k > 4 ? p[4] : 0.0f, k > 5 ? p[5] : 0.0f,
                                      k > 6 ? p[6] : 0.0f, k > 7 ? p[7] : 0.0f);
        const float4 m0 = make_float4(k > 0 ? 1.0f : 0.0f, k > 1 ? 1.0f : 0.0f,
                                      k > 2 ? 1.0f : 0.0f, k > 3 ? 1.0f : 0.0f);
        const float4 m1 = make_float4(k > 4 ? 1.0f : 0.0f, k > 5 ? 1.0f : 0.0f,
                                      k > 6 ? 1.0f : 0.0f, k > 7 ? 1.0f : 0.0f);

        float4* oI = (float4*)(out + (size_t)row * 8);
        float4* oS = (float4*)(out + (size_t)NROWS * 8  + (size_t)row * 8);
        float4* oM = (float4*)(out + (size_t)NROWS * 16 + (size_t)row * 8);
        oI[0] = o0; oI[1] = o1;
        oS[0] = s0; oS[1] = s1;
        oM[0] = m0; oM[1] = m1;
        out[(size_t)NROWS * 24 + row] = (float)k;
    }
}

extern "C" void kernel_launch(void* const* d_in, const int* in_sizes, int n_in,
                              void* d_out, int out_size, void* d_ws, size_t ws_size,
                              hipStream_t stream)
{
    const float* x  = (const float*)d_in[0];
    const float* W1 = (const float*)d_in[1];
    const float* W2 = (const float*)d_in[2];
    gate_kernel<<<NROWS / RPB, 256, 0, stream>>>(x, W1, W2, (float*)d_out);
}

// Round 7
// 199.659 us; speedup vs baseline: 1.3134x; 1.3134x over previous
//
#include <hip/hip_runtime.h>
#include <math.h>

#define NROWS 16384
#define INDIM 2048
#define NE 16
#define RPB 16                    // rows per block (4 waves x 4 rows)
#define RPW 4                     // rows per wave
#define NW 4                      // waves per block
#define KSTEP 256                 // k per chunk (64 lanes x float4)
#define NITER (INDIM / KSTEP)     // 8

// (256,2): 256-reg cap — the only spill-safe point (R4: 128 cap -> AGPR acc,
// 2.7x VALU tax; R6: 170 cap -> scratch spill, WRITE_SIZE 88MB, 124us).
// W1 via LDS cuts per-CU VMEM from 2MB (16 waves x 128KB re-read, ~13us L1
// floor) to 1MB compulsory; LDS pipe serves the reuse in parallel.
__global__ __launch_bounds__(256, 2) void gate_kernel(
    const float* __restrict__ x,
    const float* __restrict__ W1,
    const float* __restrict__ W2,
    float* __restrict__ out)
{
    __shared__ float w1s[2][NE][KSTEP];   // 32 KB double-buffered W1 chunk
    __shared__ float hbuf[RPB][17];
    __shared__ float w2s[NE * NE];        // ~34 KB total -> 2 blocks/CU fit

    const int tid  = threadIdx.x;
    const int lane = tid & 63;
    const int wv   = tid >> 6;                       // 0..3
    const int row0 = blockIdx.x * RPB;

    if (tid < 64) ((float4*)w2s)[tid] = ((const float4*)W2)[tid];

    const float* xw  = x + (size_t)(row0 + wv * RPW) * INDIM + lane * 4;
    const float* w1b = W1 + lane * 4;   // + e*INDIM + c*KSTEP

    // ---- stage chunk 0 (each wave: experts 4j+wv, 1KB contiguous per inst) ----
    {
        float4 g[4];
        #pragma unroll
        for (int j = 0; j < 4; ++j)
            g[j] = *(const float4*)(w1b + (size_t)(4 * j + wv) * INDIM);
        #pragma unroll
        for (int j = 0; j < 4; ++j)
            *(float4*)&w1s[0][4 * j + wv][lane * 4] = g[j];
    }

    // preload x for iter 0
    float4 xv_cur[RPW], xv_nxt[RPW];
    #pragma unroll
    for (int r = 0; r < RPW; ++r)
        xv_cur[r] = *(const float4*)(xw + (size_t)r * INDIM);

    float acc[RPW * NE];
    #pragma unroll
    for (int i = 0; i < RPW * NE; ++i) acc[i] = 0.0f;

    __syncthreads();   // chunk 0 + w2s visible

    #pragma unroll 1
    for (int c = 0; c < NITER; ++c) {
        // Issue order matters (vmcnt is in-order): W1-stage loads FIRST, then
        // x prefetch, so the ds_write's wait never blocks on the x HBM loads.
        float4 g[4];
        if (c + 1 < NITER) {
            #pragma unroll
            for (int j = 0; j < 4; ++j)
                g[j] = *(const float4*)(w1b + (size_t)(4 * j + wv) * INDIM
                                            + (size_t)(c + 1) * KSTEP);
            #pragma unroll
            for (int r = 0; r < RPW; ++r)
                xv_nxt[r] = *(const float4*)(xw + (size_t)r * INDIM
                                                + (size_t)(c + 1) * KSTEP);
            #pragma unroll
            for (int j = 0; j < 4; ++j)
                *(float4*)&w1s[(c + 1) & 1][4 * j + wv][lane * 4] = g[j];
        }

        // compute chunk c: W1 from LDS (b128), x from registers
        const float* wc = &w1s[c & 1][0][0];
        #pragma unroll
        for (int e = 0; e < NE; ++e) {
            const float4 wq = *(const float4*)(wc + e * KSTEP + lane * 4);
            #pragma unroll
            for (int r = 0; r < RPW; ++r) {
                float a = acc[r * NE + e];
                a = fmaf(xv_cur[r].x, wq.x, a);
                a = fmaf(xv_cur[r].y, wq.y, a);
                a = fmaf(xv_cur[r].z, wq.z, a);
                a = fmaf(xv_cur[r].w, wq.w, a);
                acc[r * NE + e] = a;
            }
        }
        __syncthreads();   // reads of buf[c&1] done; writes of buf[(c+1)&1] visible
        #pragma unroll
        for (int r = 0; r < RPW; ++r) xv_cur[r] = xv_nxt[r];
    }

    // ---- folding butterfly: reduce 64 values across 64 lanes in 63 shuffles ----
    #pragma unroll
    for (int s = 0; s < 6; ++s) {
        const int m = 1 << s;
        const int h = 32 >> s;
        const int b = (lane >> s) & 1;
        #pragma unroll
        for (int i = 0; i < h; ++i) {
            const float keep = b ? acc[i + h] : acc[i];
            const float send = b ? acc[i] : acc[i + h];
            acc[i] = keep + __shfl_xor(send, m, 64);
        }
    }
    {
        int v = 0;
        #pragma unroll
        for (int s = 0; s < 6; ++s) v |= ((lane >> s) & 1) << (5 - s);
        hbuf[wv * RPW + (v >> 4)][v & 15] = tanhf(acc[0]);
    }
    __syncthreads();

    // ---- per-row tail: logits, sort, softmax, k policy, outputs ----
    if (tid < RPB) {
        const int r   = tid;
        const int row = row0 + r;

        float hr[NE];
        #pragma unroll
        for (int e = 0; e < NE; ++e) hr[e] = hbuf[r][e];

        float v[NE];
        int   idx[NE];
        #pragma unroll
        for (int f = 0; f < NE; ++f) {
            float s = 0.0f;
            #pragma unroll
            for (int j = 0; j < 4; ++j) {
                const float4 w = ((const float4*)w2s)[f * 4 + j];
                s = fmaf(hr[4 * j + 0], w.x, s);
                s = fmaf(hr[4 * j + 1], w.y, s);
                s = fmaf(hr[4 * j + 2], w.z, s);
                s = fmaf(hr[4 * j + 3], w.w, s);
            }
            v[f]   = s / 0.7f;
            idx[f] = f;
        }

        // bitonic sort on key (-value, index): stable descending argsort
        #pragma unroll
        for (int ksz = 2; ksz <= 16; ksz <<= 1) {
            #pragma unroll
            for (int jsz = ksz >> 1; jsz >= 1; jsz >>= 1) {
                #pragma unroll
                for (int i = 0; i < 16; ++i) {
                    const int l = i ^ jsz;
                    if (l > i) {
                        const bool asc   = ((i & ksz) == 0);
                        const bool keyGt = (v[i] < v[l]) ||
                                           (v[i] == v[l] && idx[i] > idx[l]);
                        if (keyGt == asc) {
                            float tv = v[i]; v[i] = v[l]; v[l] = tv;
                            int   ti = idx[i]; idx[i] = idx[l]; idx[l] = ti;
                        }
                    }
                }
            }
        }

        float p[NE];
        float tot = 0.0f;
        #pragma unroll
        for (int i = 0; i < NE; ++i) { p[i] = expf(v[i] - v[0]); tot += p[i]; }
        #pragma unroll
        for (int i = 0; i < NE; ++i) p[i] = p[i] / tot;

        float cum[NE];
        cum[0] = p[0];
        #pragma unroll
        for (int i = 1; i < NE; ++i) cum[i] = cum[i - 1] + p[i];

        int k = NE;
        #pragma unroll
        for (int i = NE - 1; i >= 0; --i) if (cum[i] >= 0.92f) k = i + 1;

        if ((p[0] >= 0.46f) && ((p[0] - p[1]) >= 0.1f)) k = 1;
        if ((k > 2) && ((cum[1] >= 0.82f) || (p[2] <= 0.12f) || ((p[1] - p[2]) <= 0.03f)))
            k = 2;
        k = k < 1 ? 1 : (k > 3 ? 3 : k);

        const float4 o0 = make_float4((float)idx[0], (float)idx[1], (float)idx[2], (float)idx[3]);
        const float4 o1 = make_float4((float)idx[4], (float)idx[5], (float)idx[6], (float)idx[7]);
        const float4 s0 = make_float4(k > 0 ? p[0] : 0.0f, k > 1 ? p[1] : 0.0f,
                                      k > 2 ? p[2] : 0.0f, k > 3 ? p[3] : 0.0f);
        const float4 s1 = make_float4(k > 4 ? p[4] : 0.0f, k > 5 ? p[5] : 0.0f,
                                      k > 6 ? p[6] : 0.0f, k > 7 ? p[7] : 0.0f);
        const float4 m0 = make_float4(k > 0 ? 1.0f : 0.0f, k > 1 ? 1.0f : 0.0f,
                                      k > 2 ? 1.0f : 0.0f, k > 3 ? 1.0f : 0.0f);
        const float4 m1 = make_float4(k > 4 ? 1.0f : 0.0f, k > 5 ? 1.0f : 0.0f,
                                      k > 6 ? 1.0f : 0.0f, k > 7 ? 1.0f : 0.0f);

        float4* oI = (float4*)(out + (size_t)row * 8);
        float4* oS = (float4*)(out + (size_t)NROWS * 8  + (size_t)row * 8);
        float4* oM = (float4*)(out + (size_t)NROWS * 16 + (size_t)row * 8);
        oI[0] = o0; oI[1] = o1;
        oS[0] = s0; oS[1] = s1;
        oM[0] = m0; oM[1] = m1;
        out[(size_t)NROWS * 24 + row] = (float)k;
    }
}

extern "C" void kernel_launch(void* const* d_in, const int* in_sizes, int n_in,
                              void* d_out, int out_size, void* d_ws, size_t ws_size,
                              hipStream_t stream)
{
    const float* x  = (const float*)d_in[0];
    const float* W1 = (const float*)d_in[1];
    const float* W2 = (const float*)d_in[2];
    gate_kernel<<<NROWS / RPB, 256, 0, stream>>>(x, W1, W2, (float*)d_out);
}